// Round 11
// baseline (534.586 us; speedup 1.0000x reference)
//
#include <hip/hip_runtime.h>
#include <hip/hip_bf16.h>
#include <stdint.h>

// MultiHeadAttentionBlock: q,k,v [4,2048,768] f32; w_q/k/v/o [768,768] f32 ([out,in]).
// cvt_all->bf16; fused QKV projection GEMM (Q scaled log2e/8; V transposed [bh][dv][s]);
// flash attention (16 q-rows/wave for 2x occupancy [R9: latency-bound at 3 waves/SIMD],
// K/V direct from L2, no barriers, per-lane partial sums, reduction-free defer-max,
// T5 setprio, T1 XCD swizzle); output GEMM -> f32. Workspace ~80.2 MiB (ao aliases qb).
// R10: resubmission of the unmeasured R9 kernel (acquisition timeout). L2-BW floor of
// the no-staging attn = 3.1 GB / 36.9 TB/s ~= 84 us; decision tree in journal.

typedef __attribute__((ext_vector_type(8))) short short8;
typedef __attribute__((ext_vector_type(4))) float f32x4;
typedef __attribute__((ext_vector_type(4))) unsigned short us4;
typedef __attribute__((ext_vector_type(4))) float fl4;

#define DMODEL 768
#define SEQ    2048
#define NH     12
#define DKH    64
#define BATCH  4
#define MTOT   (BATCH*SEQ)   // 8192

__device__ __forceinline__ unsigned short f2bf(float x){
  unsigned u = __builtin_bit_cast(unsigned, x);
  u += 0x7fffu + ((u>>16)&1u);           // RNE
  return (unsigned short)(u>>16);
}

typedef unsigned int u32;
typedef __attribute__((address_space(1))) const u32 gu32;
typedef __attribute__((address_space(3))) u32 lu32;
__device__ __forceinline__ void gload_lds16(const void* g, void* l){
  __builtin_amdgcn_global_load_lds((gu32*)g, (lu32*)l, 16, 0, 0);
}

// ---------------- conversion (single launch) ----------------
// regions: 3 x 6144 blocks (q,k,v: 6,291,456 f32 each) + 4 x 576 blocks (weights).
__global__ void cvt_all(const float* __restrict__ q, const float* __restrict__ k,
                        const float* __restrict__ v,
                        const float* __restrict__ wq, const float* __restrict__ wk,
                        const float* __restrict__ wv, const float* __restrict__ wo,
                        unsigned short* __restrict__ oq, unsigned short* __restrict__ ok,
                        unsigned short* __restrict__ ov,
                        unsigned short* __restrict__ owq, unsigned short* __restrict__ owk,
                        unsigned short* __restrict__ owv, unsigned short* __restrict__ owo)
{
  int bid = blockIdx.x;
  const float* s; unsigned short* d; int off;
  if (bid < 3*6144){
    int r = bid / 6144; off = bid - r*6144;
    s = (r==0)? q : (r==1)? k : v;
    d = (r==0)? oq : (r==1)? ok : ov;
  } else {
    int b2 = bid - 3*6144;
    int r = b2 / 576; off = b2 - r*576;
    s = (r==0)? wq : (r==1)? wk : (r==2)? wv : wo;
    d = (r==0)? owq : (r==1)? owk : (r==2)? owv : owo;
  }
  size_t i = (size_t)off*256 + threadIdx.x;
  fl4 x = ((const fl4*)s)[i];
  us4 o;
  o.x=f2bf(x.x); o.y=f2bf(x.y); o.z=f2bf(x.z); o.w=f2bf(x.w);
  ((us4*)d)[i] = o;
}

// ---------------- shared GEMM core ----------------
// X [M][768] bf16 row-major, W [768][768] bf16 row-major ([out,in] => B^T form).
// 128x128 tile, BK=64, 4 waves (2x2 of 64x64), mfma 16x16x32 bf16.
// LDS: linear [128][64], 16B-chunk XOR swizzle (chunk ^= row&7) on BOTH the global
// source of global_load_lds and the ds_read address.
__device__ __forceinline__ void gemm_core(const unsigned short* __restrict__ A,
                                          const unsigned short* __restrict__ B,
                                          unsigned short* ldsA, unsigned short* ldsB,
                                          int m0, int n0, int t, f32x4 (&acc)[4][4])
{
  const int w = t>>6, l = t&63;
  const int wr = (w>>1)*64, wc = (w&1)*64;
  for (int kt=0; kt<DMODEL/64; ++kt){
    const int k0 = kt*64;
    #pragma unroll
    for (int i=0;i<4;++i){
      int idx = i*256 + t;              // 0..1023 16B chunks
      int row = idx>>3, slot = idx&7;
      int c = slot ^ (row&7);           // inverse-swizzled global source
      gload_lds16(A + (size_t)(m0+row)*DMODEL + k0 + c*8, &ldsA[idx*8]);
      gload_lds16(B + (size_t)(n0+row)*DMODEL + k0 + c*8, &ldsB[idx*8]);
    }
    __syncthreads();

    short8 af[4][2], bf_[4][2];
    #pragma unroll
    for (int ks=0; ks<2; ++ks){
      #pragma unroll
      for (int x=0;x<4;++x){
        int ra = wr + x*16 + (l&15);
        af[x][ks]  = *(const short8*)&ldsA[ra*64 + (((ks*4+(l>>4)) ^ (ra&7))<<3)];
        int rb = wc + x*16 + (l&15);
        bf_[x][ks] = *(const short8*)&ldsB[rb*64 + (((ks*4+(l>>4)) ^ (rb&7))<<3)];
      }
    }
    #pragma unroll
    for (int ks=0; ks<2; ++ks)
      #pragma unroll
      for (int mt=0;mt<4;++mt)
        #pragma unroll
        for (int nt=0;nt<4;++nt)
          acc[mt][nt] = __builtin_amdgcn_mfma_f32_16x16x32_bf16(af[mt][ks], bf_[nt][ks], acc[mt][nt], 0,0,0);
    __syncthreads();
  }
}

// Fused QKV projection: blockIdx.z selects {Q,K,V}.
// z=0: Qh [bh][s][64] bf16, scale log2e/8. z=1: Kh same layout. z=2: Vt [bh][dv][s] bf16
// (j-packed us4 stores: 4 consecutive s per fragment -> one aligned 8B store).
__global__ __launch_bounds__(256)
void gemm_qkv(const unsigned short* __restrict__ qb, const unsigned short* __restrict__ kb,
              const unsigned short* __restrict__ vb,
              const unsigned short* __restrict__ wqb, const unsigned short* __restrict__ wkb,
              const unsigned short* __restrict__ wvb,
              unsigned short* __restrict__ Qh, unsigned short* __restrict__ Kh,
              unsigned short* __restrict__ Vt)
{
  __shared__ unsigned short ldsA[128*64];
  __shared__ unsigned short ldsB[128*64];
  const int t = threadIdx.x;
  const int z = blockIdx.z;
  const unsigned short* A = (z==0)? qb : (z==1)? kb : vb;
  const unsigned short* B = (z==0)? wqb : (z==1)? wkb : wvb;
  unsigned short* out     = (z==0)? Qh : (z==1)? Kh : Vt;
  const float oscale      = (z==0)? 0.18033688011112042f : 1.0f;  // log2(e)/sqrt(64)

  const int m0 = blockIdx.x*128, n0 = blockIdx.y*128;
  const int w = t>>6, l = t&63;
  const int wr = (w>>1)*64, wc = (w&1)*64;

  f32x4 acc[4][4] = {};
  gemm_core(A, B, ldsA, ldsB, m0, n0, t, acc);

  if (z==2){
    // V transposed epilogue: m -> s (consecutive in j), n -> (h, dv). Pack 4 j into us4.
    #pragma unroll
    for (int mt=0;mt<4;++mt){
      #pragma unroll
      for (int nt=0;nt<4;++nt){
        int mbase = m0 + wr + mt*16 + ((l>>4)<<2);   // + j, j=0..3 consecutive
        int n = n0 + wc + nt*16 + (l&15);
        int b_ = mbase>>11, s_ = mbase&2047, h_ = n>>6, d_ = n&63;
        us4 o;
        o.x = f2bf(acc[mt][nt][0]); o.y = f2bf(acc[mt][nt][1]);
        o.z = f2bf(acc[mt][nt][2]); o.w = f2bf(acc[mt][nt][3]);
        *(us4*)&out[((size_t)((b_*NH + h_)*DKH + d_)<<11) + s_] = o;
      }
    }
  } else {
    #pragma unroll
    for (int mt=0;mt<4;++mt){
      #pragma unroll
      for (int nt=0;nt<4;++nt){
        #pragma unroll
        for (int j=0;j<4;++j){
          float v = acc[mt][nt][j] * oscale;
          int m = m0 + wr + mt*16 + ((l>>4)<<2) + j;   // C/D: col=lane&15, row=(lane>>4)*4+j
          int n = n0 + wc + nt*16 + (l&15);
          int b_ = m>>11, s_ = m&2047, h_ = n>>6, d_ = n&63;
          out[((size_t)((b_*NH + h_)*SEQ + s_)<<6) + d_] = f2bf(v);    // head-split
        }
      }
    }
  }
}

// Output GEMM: ao [8192][768] bf16 @ wo^T -> f32 [8192][768]
__global__ __launch_bounds__(256)
void gemm_out(const unsigned short* __restrict__ A,
              const unsigned short* __restrict__ B,
              float* __restrict__ out)
{
  __shared__ unsigned short ldsA[128*64];
  __shared__ unsigned short ldsB[128*64];
  const int t = threadIdx.x;
  const int m0 = blockIdx.x*128, n0 = blockIdx.y*128;
  const int w = t>>6, l = t&63;
  const int wr = (w>>1)*64, wc = (w&1)*64;

  f32x4 acc[4][4] = {};
  gemm_core(A, B, ldsA, ldsB, m0, n0, t, acc);

  #pragma unroll
  for (int mt=0;mt<4;++mt){
    #pragma unroll
    for (int nt=0;nt<4;++nt){
      #pragma unroll
      for (int j=0;j<4;++j){
        int m = m0 + wr + mt*16 + ((l>>4)<<2) + j;
        int n = n0 + wc + nt*16 + (l&15);
        out[(size_t)m*DMODEL + n] = acc[mt][nt][j];
      }
    }
  }
}

// ---------------- flash attention ----------------
// 16 q-rows per wave => grid 1536 blocks (6/CU supplied, VGPR-capped ~4-5 waves/SIMD).
// Per block: 64 q rows (4 waves x 16), 32 KV tiles of 64 keys.
// K [bh][s][64], Vt [bh][dv][s] bf16, read DIRECT from global (L2-resident).
// No barriers (per-wave Pl). Per-lane partial sums; reduction-free defer-max
// fast path; slow path (first tile / growth > 8*log2e) reduces + rescales.
// T1 XCD swizzle: wgid%8 = XCD residue; 6 heads (3 MB KV) per residue. Bijective.
__global__ __launch_bounds__(256)
void attn_fwd(const unsigned short* __restrict__ Qh,
              const unsigned short* __restrict__ Kh,
              const unsigned short* __restrict__ Vt,
              unsigned short* __restrict__ Out)
{
  __shared__ unsigned short Pl[4][16][72];    // per-wave P [qrow][key], +8 pad
  const int t = threadIdx.x, w = t>>6, l = t&63;
  const int wgid = blockIdx.x;
  const int c  = wgid & 7;                    // XCD residue
  const int r  = wgid >> 3;                   // 0..191
  const int bh = c + 8*(r >> 5);              // head: h%8==c, 6 per residue
  const int qt = r & 31;                      // q-tile 0..31 (64 rows each)
  const int b_ = bh/NH, h_ = bh - b_*NH;
  const int q0 = qt*64 + w*16;
  const unsigned short* Qp = Qh + ((size_t)bh*SEQ + q0)*DKH;
  const unsigned short* Kp = Kh + (size_t)bh*SEQ*DKH;
  const unsigned short* Vp = Vt + (size_t)bh*DKH*SEQ;

  short8 qf[2];
  #pragma unroll
  for (int ks=0;ks<2;++ks)
    qf[ks] = *(const short8*)(Qp + (l&15)*DKH + ks*32 + ((l>>4)<<3));

  f32x4 O[4] = {};
  float mrow[4], lsum[4];                     // mrow uniform per 16-lane row group;
  #pragma unroll                              // lsum per-lane partial (4 keys/lane)
  for (int j=0;j<4;++j){ mrow[j] = -1e30f; lsum[j] = 0.f; }

  for (int kt=0; kt<SEQ/64; ++kt){
    const int kb = kt*64;

    // K fragments: kf[nf][ks] = K[kb + nf*16 + (l&15)][ks*32 + (l>>4)*8 ..+8]
    short8 kf[4][2];
    #pragma unroll
    for (int nf=0;nf<4;++nf)
      #pragma unroll
      for (int ks=0;ks<2;++ks)
        kf[nf][ks] = *(const short8*)(Kp + (size_t)(kb + nf*16 + (l&15))*DKH + ks*32 + ((l>>4)<<3));

    // V fragments issued early (consumed after softmax): vf[dv][kc] =
    // V^T[dv*16 + (l&15)][kb + kc*32 + (l>>4)*8 ..+8]
    short8 vf[4][2];
    #pragma unroll
    for (int dv=0;dv<4;++dv)
      #pragma unroll
      for (int kc=0;kc<2;++kc)
        vf[dv][kc] = *(const short8*)(Vp + (size_t)(dv*16 + (l&15))*SEQ + kb + kc*32 + ((l>>4)<<3));

    // S = Q @ K^T  (A=Q row=q, B=K^T col=key); 16 q-rows -> single mt tile
    f32x4 sfr[4] = {};
    __builtin_amdgcn_s_setprio(1);
    #pragma unroll
    for (int ks=0;ks<2;++ks)
      #pragma unroll
      for (int nf=0;nf<4;++nf)
        sfr[nf] = __builtin_amdgcn_mfma_f32_16x16x32_bf16(qf[ks], kf[nf][ks], sfr[nf],0,0,0);
    __builtin_amdgcn_s_setprio(0);

    // ---- softmax (base 2); row=(l>>4)*4+j, keys over (l&15, nf) ----
    float ptm[4];
    bool conj = true;
    #pragma unroll
    for (int j=0;j<4;++j){
      float tm = fmaxf(fmaxf(sfr[0][j],sfr[1][j]),fmaxf(sfr[2][j],sfr[3][j]));
      ptm[j] = tm;
      conj = conj && (tm <= mrow[j] + 11.541560327111707f);   // 8*log2(e)
    }
    if (!__all(conj)){
      #pragma unroll
      for (int j=0;j<4;++j){
        float tm = ptm[j];
        tm = fmaxf(tm, __shfl_xor(tm,1));
        tm = fmaxf(tm, __shfl_xor(tm,2));
        tm = fmaxf(tm, __shfl_xor(tm,4));
        tm = fmaxf(tm, __shfl_xor(tm,8));
        float mn = fmaxf(mrow[j], tm);
        float fs = __builtin_amdgcn_exp2f(mrow[j]-mn);        // lane-uniform in group
        mrow[j] = mn;
        lsum[j] *= fs;
        O[0][j] *= fs; O[1][j] *= fs; O[2][j] *= fs; O[3][j] *= fs;
      }
    }
    #pragma unroll
    for (int j=0;j<4;++j){
      float mn = mrow[j];
      #pragma unroll
      for (int nf=0;nf<4;++nf){
        float p = __builtin_amdgcn_exp2f(sfr[nf][j]-mn);      // <= 2^11.54
        lsum[j] += p;
        Pl[w][((l>>4)<<2)+j][(l&15)+nf*16] = f2bf(p);
      }
    }

    // O += P @ V  (A=P row=q via per-wave Pl; B=V via vf regs loaded above)
    short8 pf[2];
    #pragma unroll
    for (int kc=0;kc<2;++kc)
      pf[kc] = *(const short8*)&Pl[w][l&15][kc*32+((l>>4)<<3)];
    __builtin_amdgcn_s_setprio(1);
    #pragma unroll
    for (int kc=0;kc<2;++kc)
      #pragma unroll
      for (int dv=0;dv<4;++dv)
        O[dv] = __builtin_amdgcn_mfma_f32_16x16x32_bf16(pf[kc], vf[dv][kc], O[dv],0,0,0);
    __builtin_amdgcn_s_setprio(0);
  }

  // epilogue: one 4-shfl sum reduction per row, then normalize+store
  float rl[4];
  #pragma unroll
  for (int j=0;j<4;++j){
    float ls = lsum[j];
    ls += __shfl_xor(ls,1); ls += __shfl_xor(ls,2);
    ls += __shfl_xor(ls,4); ls += __shfl_xor(ls,8);
    rl[j] = 1.0f/ls;
  }
  #pragma unroll
  for (int dv=0;dv<4;++dv){
    #pragma unroll
    for (int j=0;j<4;++j){
      int srow = q0 + ((l>>4)<<2) + j;
      int col  = h_*DKH + dv*16 + (l&15);
      Out[(size_t)(b_*SEQ + srow)*DMODEL + col] = f2bf(O[dv][j]*rl[j]);
    }
  }
}

// ---------------- launcher ----------------
extern "C" void kernel_launch(void* const* d_in, const int* in_sizes, int n_in,
                              void* d_out, int out_size, void* d_ws, size_t ws_size,
                              hipStream_t stream)
{
  const float* q  = (const float*)d_in[0];
  const float* k  = (const float*)d_in[1];
  const float* v  = (const float*)d_in[2];
  const float* wq = (const float*)d_in[3];
  const float* wk = (const float*)d_in[4];
  const float* wv = (const float*)d_in[5];
  const float* wo = (const float*)d_in[6];

  const size_t SZ_T = (size_t)MTOT*DMODEL;     // 6,291,456
  const size_t SZ_W = (size_t)DMODEL*DMODEL;   // 589,824
  unsigned short* qb  = (unsigned short*)d_ws;
  unsigned short* kb  = qb  + SZ_T;
  unsigned short* vb  = kb  + SZ_T;
  unsigned short* wqb = vb  + SZ_T;
  unsigned short* wkb = wqb + SZ_W;
  unsigned short* wvb = wkb + SZ_W;
  unsigned short* wob = wvb + SZ_W;
  unsigned short* Qh  = wob + SZ_W;            // [48][2048][64]
  unsigned short* Kh  = Qh  + SZ_T;
  unsigned short* Vt  = Kh  + SZ_T;            // [48][64][2048]
  unsigned short* ao  = qb;                    // attn out [8192][768] — aliases qb (dead after Q-proj)

  cvt_all<<<dim3(3*6144 + 4*576), 256, 0, stream>>>(q, k, v, wq, wk, wv, wo,
                                                    qb, kb, vb, wqb, wkb, wvb, wob);

  gemm_qkv<<<dim3(MTOT/128, DMODEL/128, 3), 256, 0, stream>>>(qb, kb, vb, wqb, wkb, wvb, Qh, Kh, Vt);

  attn_fwd<<<dim3(32*48), 256, 0, stream>>>(Qh, Kh, Vt, ao);

  gemm_out<<<dim3(MTOT/128, DMODEL/128), 256, 0, stream>>>(ao, wob, (float*)d_out);
}

// Round 12
// 310.183 us; speedup vs baseline: 1.7235x; 1.7235x over previous
//
#include <hip/hip_runtime.h>
#include <hip/hip_bf16.h>
#include <stdint.h>

// MultiHeadAttentionBlock: q,k,v [4,2048,768] f32; w_q/k/v/o [768,768] f32 ([out,in]).
// cvt_all->bf16; fused QKV projection GEMM (Q scaled log2e/8; V transposed [bh][dv][s]);
// flash attention R11: LDS-staged double-buffered K/V (R10 counters: no-staging saturates
// ~34 GB/s/CU vector-mem request ceiling; 4 waves re-loaded the same tile 4x), 32 q-rows/
// wave, 768 blocks, XOR-swizzled tiles, per-lane partial softmax, defer-max, setprio,
// XCD swizzle; output GEMM -> f32. Workspace ~80.2 MiB (ao aliases qb).

typedef __attribute__((ext_vector_type(8))) short short8;
typedef __attribute__((ext_vector_type(4))) float f32x4;
typedef __attribute__((ext_vector_type(4))) unsigned short us4;
typedef __attribute__((ext_vector_type(4))) float fl4;

#define DMODEL 768
#define SEQ    2048
#define NH     12
#define DKH    64
#define BATCH  4
#define MTOT   (BATCH*SEQ)   // 8192

__device__ __forceinline__ unsigned short f2bf(float x){
  unsigned u = __builtin_bit_cast(unsigned, x);
  u += 0x7fffu + ((u>>16)&1u);           // RNE
  return (unsigned short)(u>>16);
}

typedef unsigned int u32;
typedef __attribute__((address_space(1))) const u32 gu32;
typedef __attribute__((address_space(3))) u32 lu32;
__device__ __forceinline__ void gload_lds16(const void* g, void* l){
  __builtin_amdgcn_global_load_lds((gu32*)g, (lu32*)l, 16, 0, 0);
}

// ---------------- conversion (single launch) ----------------
__global__ void cvt_all(const float* __restrict__ q, const float* __restrict__ k,
                        const float* __restrict__ v,
                        const float* __restrict__ wq, const float* __restrict__ wk,
                        const float* __restrict__ wv, const float* __restrict__ wo,
                        unsigned short* __restrict__ oq, unsigned short* __restrict__ ok,
                        unsigned short* __restrict__ ov,
                        unsigned short* __restrict__ owq, unsigned short* __restrict__ owk,
                        unsigned short* __restrict__ owv, unsigned short* __restrict__ owo)
{
  int bid = blockIdx.x;
  const float* s; unsigned short* d; int off;
  if (bid < 3*6144){
    int r = bid / 6144; off = bid - r*6144;
    s = (r==0)? q : (r==1)? k : v;
    d = (r==0)? oq : (r==1)? ok : ov;
  } else {
    int b2 = bid - 3*6144;
    int r = b2 / 576; off = b2 - r*576;
    s = (r==0)? wq : (r==1)? wk : (r==2)? wv : wo;
    d = (r==0)? owq : (r==1)? owk : (r==2)? owv : owo;
  }
  size_t i = (size_t)off*256 + threadIdx.x;
  fl4 x = ((const fl4*)s)[i];
  us4 o;
  o.x=f2bf(x.x); o.y=f2bf(x.y); o.z=f2bf(x.z); o.w=f2bf(x.w);
  ((us4*)d)[i] = o;
}

// ---------------- shared GEMM core ----------------
__device__ __forceinline__ void gemm_core(const unsigned short* __restrict__ A,
                                          const unsigned short* __restrict__ B,
                                          unsigned short* ldsA, unsigned short* ldsB,
                                          int m0, int n0, int t, f32x4 (&acc)[4][4])
{
  const int w = t>>6, l = t&63;
  const int wr = (w>>1)*64, wc = (w&1)*64;
  for (int kt=0; kt<DMODEL/64; ++kt){
    const int k0 = kt*64;
    #pragma unroll
    for (int i=0;i<4;++i){
      int idx = i*256 + t;              // 0..1023 16B chunks
      int row = idx>>3, slot = idx&7;
      int c = slot ^ (row&7);           // inverse-swizzled global source
      gload_lds16(A + (size_t)(m0+row)*DMODEL + k0 + c*8, &ldsA[idx*8]);
      gload_lds16(B + (size_t)(n0+row)*DMODEL + k0 + c*8, &ldsB[idx*8]);
    }
    __syncthreads();

    short8 af[4][2], bf_[4][2];
    #pragma unroll
    for (int ks=0; ks<2; ++ks){
      #pragma unroll
      for (int x=0;x<4;++x){
        int ra = wr + x*16 + (l&15);
        af[x][ks]  = *(const short8*)&ldsA[ra*64 + (((ks*4+(l>>4)) ^ (ra&7))<<3)];
        int rb = wc + x*16 + (l&15);
        bf_[x][ks] = *(const short8*)&ldsB[rb*64 + (((ks*4+(l>>4)) ^ (rb&7))<<3)];
      }
    }
    #pragma unroll
    for (int ks=0; ks<2; ++ks)
      #pragma unroll
      for (int mt=0;mt<4;++mt)
        #pragma unroll
        for (int nt=0;nt<4;++nt)
          acc[mt][nt] = __builtin_amdgcn_mfma_f32_16x16x32_bf16(af[mt][ks], bf_[nt][ks], acc[mt][nt], 0,0,0);
    __syncthreads();
  }
}

// Fused QKV projection: blockIdx.z selects {Q,K,V}.
__global__ __launch_bounds__(256)
void gemm_qkv(const unsigned short* __restrict__ qb, const unsigned short* __restrict__ kb,
              const unsigned short* __restrict__ vb,
              const unsigned short* __restrict__ wqb, const unsigned short* __restrict__ wkb,
              const unsigned short* __restrict__ wvb,
              unsigned short* __restrict__ Qh, unsigned short* __restrict__ Kh,
              unsigned short* __restrict__ Vt)
{
  __shared__ unsigned short ldsA[128*64];
  __shared__ unsigned short ldsB[128*64];
  const int t = threadIdx.x;
  const int z = blockIdx.z;
  const unsigned short* A = (z==0)? qb : (z==1)? kb : vb;
  const unsigned short* B = (z==0)? wqb : (z==1)? wkb : wvb;
  unsigned short* out     = (z==0)? Qh : (z==1)? Kh : Vt;
  const float oscale      = (z==0)? 0.18033688011112042f : 1.0f;  // log2(e)/sqrt(64)

  const int m0 = blockIdx.x*128, n0 = blockIdx.y*128;
  const int w = t>>6, l = t&63;
  const int wr = (w>>1)*64, wc = (w&1)*64;

  f32x4 acc[4][4] = {};
  gemm_core(A, B, ldsA, ldsB, m0, n0, t, acc);

  if (z==2){
    // V transposed epilogue: pack 4 consecutive s into one us4 store.
    #pragma unroll
    for (int mt=0;mt<4;++mt){
      #pragma unroll
      for (int nt=0;nt<4;++nt){
        int mbase = m0 + wr + mt*16 + ((l>>4)<<2);   // + j, j=0..3 consecutive
        int n = n0 + wc + nt*16 + (l&15);
        int b_ = mbase>>11, s_ = mbase&2047, h_ = n>>6, d_ = n&63;
        us4 o;
        o.x = f2bf(acc[mt][nt][0]); o.y = f2bf(acc[mt][nt][1]);
        o.z = f2bf(acc[mt][nt][2]); o.w = f2bf(acc[mt][nt][3]);
        *(us4*)&out[((size_t)((b_*NH + h_)*DKH + d_)<<11) + s_] = o;
      }
    }
  } else {
    #pragma unroll
    for (int mt=0;mt<4;++mt){
      #pragma unroll
      for (int nt=0;nt<4;++nt){
        #pragma unroll
        for (int j=0;j<4;++j){
          float v = acc[mt][nt][j] * oscale;
          int m = m0 + wr + mt*16 + ((l>>4)<<2) + j;   // C/D: col=lane&15, row=(lane>>4)*4+j
          int n = n0 + wc + nt*16 + (l&15);
          int b_ = m>>11, s_ = m&2047, h_ = n>>6, d_ = n&63;
          out[((size_t)((b_*NH + h_)*SEQ + s_)<<6) + d_] = f2bf(v);    // head-split
        }
      }
    }
  }
}

// Output GEMM: ao [8192][768] bf16 @ wo^T -> f32 [8192][768]
__global__ __launch_bounds__(256)
void gemm_out(const unsigned short* __restrict__ A,
              const unsigned short* __restrict__ B,
              float* __restrict__ out)
{
  __shared__ unsigned short ldsA[128*64];
  __shared__ unsigned short ldsB[128*64];
  const int t = threadIdx.x;
  const int m0 = blockIdx.x*128, n0 = blockIdx.y*128;
  const int w = t>>6, l = t&63;
  const int wr = (w>>1)*64, wc = (w&1)*64;

  f32x4 acc[4][4] = {};
  gemm_core(A, B, ldsA, ldsB, m0, n0, t, acc);

  #pragma unroll
  for (int mt=0;mt<4;++mt){
    #pragma unroll
    for (int nt=0;nt<4;++nt){
      #pragma unroll
      for (int j=0;j<4;++j){
        int m = m0 + wr + mt*16 + ((l>>4)<<2) + j;
        int n = n0 + wc + nt*16 + (l&15);
        out[(size_t)m*DMODEL + n] = acc[mt][nt][j];
      }
    }
  }
}

// ---------------- flash attention ----------------
// R11: K/V staged in LDS once per block (double-buffered global_load_lds), shared by
// 4 waves x 32 q-rows. Grid 768 (16 qtiles x 48 heads), 3 blocks/CU (LDS 50.4 KB).
// Per tile: barrier -> issue next tile's gload_lds into other buffer -> compute current
// (loads overlap compute; next barrier's vmcnt(0) drains). XOR swizzle (chunk ^= row&7)
// on BOTH gload source and ds_read addr => 2-way conflicts (free). Softmax: per-lane
// partial sums, reduction-free defer-max fast path. T1 XCD swizzle as R8.
__global__ __launch_bounds__(256)
void attn_fwd(const unsigned short* __restrict__ Qh,
              const unsigned short* __restrict__ Kh,
              const unsigned short* __restrict__ Vt,
              unsigned short* __restrict__ Out)
{
  __shared__ unsigned short Kl[2][64*64];     // [buf][key][dim], swizzled
  __shared__ unsigned short Vl[2][64*64];     // [buf][dv][key], swizzled
  __shared__ unsigned short Pl[4][32][72];    // per-wave P [qrow][key], +8 pad
  const int t = threadIdx.x, w = t>>6, l = t&63;
  const int wgid = blockIdx.x;
  const int c  = wgid & 7;                    // XCD residue
  const int r  = wgid >> 3;                   // 0..95
  const int bh = c + 8*(r >> 4);              // head: h%8==c, 6 per residue
  const int qt = r & 15;                      // q-tile 0..15 (128 rows)
  const int b_ = bh/NH, h_ = bh - b_*NH;
  const int q0 = qt*128 + w*32;
  const unsigned short* Qp = Qh + ((size_t)bh*SEQ + q0)*DKH;
  const unsigned short* Kp = Kh + (size_t)bh*SEQ*DKH;
  const unsigned short* Vp = Vt + (size_t)bh*DKH*SEQ;

  // staging geometry: 512 16B-chunks per 8KB tile; 2 K + 2 V chunks per thread.
  const int r0 = t>>3,        s0_ = t&7;
  const int r1 = (256+t)>>3,  s1_ = (256+t)&7;
  const int c0 = s0_ ^ (r0&7), c1 = s1_ ^ (r1&7);   // inverse-swizzled source chunk

#define STAGE(b, kb_) do { \
    gload_lds16(Kp + (size_t)((kb_)+r0)*DKH + c0*8, &Kl[b][(0*256+t)*8]); \
    gload_lds16(Kp + (size_t)((kb_)+r1)*DKH + c1*8, &Kl[b][(1*256+t)*8]); \
    gload_lds16(Vp + (size_t)r0*SEQ + (kb_) + c0*8, &Vl[b][(0*256+t)*8]); \
    gload_lds16(Vp + (size_t)r1*SEQ + (kb_) + c1*8, &Vl[b][(1*256+t)*8]); \
  } while(0)

  short8 qf[2][2];
  #pragma unroll
  for (int mt=0;mt<2;++mt)
    #pragma unroll
    for (int ks=0;ks<2;++ks)
      qf[mt][ks] = *(const short8*)(Qp + (mt*16+(l&15))*DKH + ks*32 + ((l>>4)<<3));

  f32x4 O[2][4] = {};
  float mrow[2][4], lsum[2][4];               // mrow uniform per 16-lane row group;
  #pragma unroll                              // lsum per-lane partial (4 keys/lane)
  for (int mt=0;mt<2;++mt)
    #pragma unroll
    for (int j=0;j<4;++j){ mrow[mt][j] = -1e30f; lsum[mt][j] = 0.f; }

  STAGE(0, 0);                                // prologue: tile 0 -> buf 0

  for (int kt=0; kt<SEQ/64; ++kt){
    const int cur = kt&1;
    __syncthreads();                          // drains gload_lds; buf[cur] ready
    if (kt+1 < SEQ/64) STAGE(cur^1, (kt+1)*64);   // overlap with compute below

    const unsigned short* Kc = Kl[cur];
    const unsigned short* Vc = Vl[cur];

    // fragments from swizzled LDS: chunk' = (ks*4 + (l>>4)) ^ (l&7)
    short8 kf[4][2], vf[4][2];
    #pragma unroll
    for (int nf=0;nf<4;++nf)
      #pragma unroll
      for (int ks=0;ks<2;++ks)
        kf[nf][ks] = *(const short8*)&Kc[(nf*16+(l&15))*64 + (((ks*4+(l>>4)) ^ (l&7))<<3)];
    #pragma unroll
    for (int dv=0;dv<4;++dv)
      #pragma unroll
      for (int kc=0;kc<2;++kc)
        vf[dv][kc] = *(const short8*)&Vc[(dv*16+(l&15))*64 + (((kc*4+(l>>4)) ^ (l&7))<<3)];

    // S = Q @ K^T
    f32x4 sfr[2][4] = {};
    __builtin_amdgcn_s_setprio(1);
    #pragma unroll
    for (int ks=0;ks<2;++ks)
      #pragma unroll
      for (int mt=0;mt<2;++mt)
        #pragma unroll
        for (int nf=0;nf<4;++nf)
          sfr[mt][nf] = __builtin_amdgcn_mfma_f32_16x16x32_bf16(qf[mt][ks], kf[nf][ks], sfr[mt][nf],0,0,0);
    __builtin_amdgcn_s_setprio(0);

    // ---- softmax (base 2); row=(l>>4)*4+j, keys over (l&15, nf) ----
    float ptm[2][4];
    bool conj = true;
    #pragma unroll
    for (int mt=0;mt<2;++mt){
      #pragma unroll
      for (int j=0;j<4;++j){
        float tm = fmaxf(fmaxf(sfr[mt][0][j],sfr[mt][1][j]),fmaxf(sfr[mt][2][j],sfr[mt][3][j]));
        ptm[mt][j] = tm;
        conj = conj && (tm <= mrow[mt][j] + 11.541560327111707f);   // 8*log2(e)
      }
    }
    if (!__all(conj)){
      #pragma unroll
      for (int mt=0;mt<2;++mt){
        #pragma unroll
        for (int j=0;j<4;++j){
          float tm = ptm[mt][j];
          tm = fmaxf(tm, __shfl_xor(tm,1));
          tm = fmaxf(tm, __shfl_xor(tm,2));
          tm = fmaxf(tm, __shfl_xor(tm,4));
          tm = fmaxf(tm, __shfl_xor(tm,8));
          float mn = fmaxf(mrow[mt][j], tm);
          float fs = __builtin_amdgcn_exp2f(mrow[mt][j]-mn);    // lane-uniform in group
          mrow[mt][j] = mn;
          lsum[mt][j] *= fs;
          #pragma unroll
          for (int dv=0;dv<4;++dv) O[mt][dv][j] *= fs;
        }
      }
    }
    #pragma unroll
    for (int mt=0;mt<2;++mt){
      #pragma unroll
      for (int j=0;j<4;++j){
        float mn = mrow[mt][j];
        #pragma unroll
        for (int nf=0;nf<4;++nf){
          float p = __builtin_amdgcn_exp2f(sfr[mt][nf][j]-mn);  // <= 2^11.54
          lsum[mt][j] += p;
          Pl[w][mt*16+((l>>4)<<2)+j][(l&15)+nf*16] = f2bf(p);
        }
      }
    }

    // O += P @ V
    short8 pf[2][2];
    #pragma unroll
    for (int mt=0;mt<2;++mt)
      #pragma unroll
      for (int kc=0;kc<2;++kc)
        pf[mt][kc] = *(const short8*)&Pl[w][mt*16+(l&15)][kc*32+((l>>4)<<3)];
    __builtin_amdgcn_s_setprio(1);
    #pragma unroll
    for (int kc=0;kc<2;++kc)
      #pragma unroll
      for (int mt=0;mt<2;++mt)
        #pragma unroll
        for (int dv=0;dv<4;++dv)
          O[mt][dv] = __builtin_amdgcn_mfma_f32_16x16x32_bf16(pf[mt][kc], vf[dv][kc], O[mt][dv],0,0,0);
    __builtin_amdgcn_s_setprio(0);
  }
#undef STAGE

  // epilogue: one 4-shfl sum reduction per row, then normalize+store
  #pragma unroll
  for (int mt=0;mt<2;++mt){
    float rl[4];
    #pragma unroll
    for (int j=0;j<4;++j){
      float ls = lsum[mt][j];
      ls += __shfl_xor(ls,1); ls += __shfl_xor(ls,2);
      ls += __shfl_xor(ls,4); ls += __shfl_xor(ls,8);
      rl[j] = 1.0f/ls;
    }
    #pragma unroll
    for (int dv=0;dv<4;++dv){
      #pragma unroll
      for (int j=0;j<4;++j){
        int srow = q0 + mt*16 + ((l>>4)<<2) + j;
        int col  = h_*DKH + dv*16 + (l&15);
        Out[(size_t)(b_*SEQ + srow)*DMODEL + col] = f2bf(O[mt][dv][j]*rl[j]);
      }
    }
  }
}

// ---------------- launcher ----------------
extern "C" void kernel_launch(void* const* d_in, const int* in_sizes, int n_in,
                              void* d_out, int out_size, void* d_ws, size_t ws_size,
                              hipStream_t stream)
{
  const float* q  = (const float*)d_in[0];
  const float* k  = (const float*)d_in[1];
  const float* v  = (const float*)d_in[2];
  const float* wq = (const float*)d_in[3];
  const float* wk = (const float*)d_in[4];
  const float* wv = (const float*)d_in[5];
  const float* wo = (const float*)d_in[6];

  const size_t SZ_T = (size_t)MTOT*DMODEL;     // 6,291,456
  const size_t SZ_W = (size_t)DMODEL*DMODEL;   // 589,824
  unsigned short* qb  = (unsigned short*)d_ws;
  unsigned short* kb  = qb  + SZ_T;
  unsigned short* vb  = kb  + SZ_T;
  unsigned short* wqb = vb  + SZ_T;
  unsigned short* wkb = wqb + SZ_W;
  unsigned short* wvb = wkb + SZ_W;
  unsigned short* wob = wvb + SZ_W;
  unsigned short* Qh  = wob + SZ_W;            // [48][2048][64]
  unsigned short* Kh  = Qh  + SZ_T;
  unsigned short* Vt  = Kh  + SZ_T;            // [48][64][2048]
  unsigned short* ao  = qb;                    // attn out [8192][768] — aliases qb (dead after Q-proj)

  cvt_all<<<dim3(3*6144 + 4*576), 256, 0, stream>>>(q, k, v, wq, wk, wv, wo,
                                                    qb, kb, vb, wqb, wkb, wvb, wob);

  gemm_qkv<<<dim3(MTOT/128, DMODEL/128, 3), 256, 0, stream>>>(qb, kb, vb, wqb, wkb, wvb, Qh, Kh, Vt);

  attn_fwd<<<dim3(16*48), 256, 0, stream>>>(Qh, Kh, Vt, ao);

  gemm_out<<<dim3(MTOT/128, DMODEL/128), 256, 0, stream>>>(ao, wob, (float*)d_out);
}